// Round 9
// baseline (134.532 us; speedup 1.0000x reference)
//
#include <hip/hip_runtime.h>
#include <math.h>

#define NHEAD 8
#define HEAD_DIM 32
#define IMG_H 32
#define IMG_W 40
#define NPIX (IMG_H*IMG_W)
#define CMAX 160
#define NITER (CMAX/8)   // 20
#define FEAT (NHEAD*HEAD_DIM)

// ===== Geometry: LOCKED bit-exact numpy-fp32 emulation =====
// R27: register-LU (explicit scalars + pivot selects, arithmetic 1:1 with
// numpy chain) -> fusable without scratch demotion. PASSED, absmax 2^-10.

__device__ __forceinline__ void np_inv3x3_reg(const float* __restrict__ M, float inv[3][3]) {
#pragma clang fp contract(off)
    float a00=M[0], a01=M[1], a02=M[2];
    float a10=M[3], a11=M[4], a12=M[5];
    float a20=M[6], a21=M[7], a22=M[8];

    // ---- kk=0: pivot search (strictly-greater update, as numpy) ----
    const float c0 = fabsf(a00), c1 = fabsf(a10), c2 = fabsf(a20);
    const bool s1 = c1 > c0;
    const float cm = s1 ? c1 : c0;
    const bool s2 = c2 > cm;
    const bool q1 = s1 && !s2;      // pivot row 1
    const bool q2 = s2;             // pivot row 2 (q1,q2 mutually exclusive)
    {   // full row swap 0 <-> p0
        const float n0 = q2 ? a20 : (q1 ? a10 : a00);
        const float n1 = q2 ? a21 : (q1 ? a11 : a01);
        const float n2 = q2 ? a22 : (q1 ? a12 : a02);
        const float m0 = q1 ? a00 : a10, m1 = q1 ? a01 : a11, m2 = q1 ? a02 : a12;
        const float r0 = q2 ? a00 : a20, r1 = q2 ? a01 : a21, r2 = q2 ? a02 : a22;
        a00=n0; a01=n1; a02=n2;
        a10=m0; a11=m1; a12=m2;
        a20=r0; a21=r1; a22=r2;
    }
    const float rp0 = 1.0f / a00;
    a10 = a10 * rp0;
    a20 = a20 * rp0;
    a11 = a11 - a10*a01;
    a12 = a12 - a10*a02;
    a21 = a21 - a20*a01;
    a22 = a22 - a20*a02;

    // ---- kk=1: pivot search over rows 1,2 ----
    const bool sB = fabsf(a21) > fabsf(a11);
    {   // full row swap 1 <-> 2 (includes factored column 0, as numpy)
        const float t0 = sB ? a20 : a10, t1 = sB ? a21 : a11, t2 = sB ? a22 : a12;
        const float u0 = sB ? a10 : a20, u1 = sB ? a11 : a21, u2 = sB ? a12 : a22;
        a10=t0; a11=t1; a12=t2;
        a20=u0; a21=u1; a22=u2;
    }
    const float rp1 = 1.0f / a11;
    a21 = a21 * rp1;
    a22 = a22 - a21*a12;
    // kk=2: pivot is row 2, no swap, no elimination.

    // ---- solve A x = e_col for col=0,1,2 (constant-trip, unrolled) ----
    #pragma unroll
    for (int col = 0; col < 3; col++) {
        float b0 = (col==0) ? 1.0f : 0.0f;
        float b1 = (col==1) ? 1.0f : 0.0f;
        float b2 = (col==2) ? 1.0f : 0.0f;
        {   // apply piv[0]
            const float w0 = q2 ? b2 : (q1 ? b1 : b0);
            const float w1 = q1 ? b0 : b1;
            const float w2 = q2 ? b0 : b2;
            b0=w0; b1=w1; b2=w2;
        }
        {   // apply piv[1]
            const float x1 = sB ? b2 : b1;
            const float x2 = sB ? b1 : b2;
            b1=x1; b2=x2;
        }
        // forward substitution (i=1:kk=0; i=2:kk=0,1)
        b1 = b1 - a10*b0;
        b2 = b2 - a20*b0;
        b2 = b2 - a21*b1;
        // back substitution (kk=2: i=0,1; kk=1: i=0; kk=0)
        b2 = b2 / a22;
        b0 = b0 - a02*b2;
        b1 = b1 - a12*b2;
        b1 = b1 / a11;
        b0 = b0 - a01*b1;
        b0 = b0 / a00;
        inv[0][col]=b0; inv[1][col]=b1; inv[2][col]=b2;
    }
}

__device__ __forceinline__ void mm3_chain(const float A[3][3], const float B[3][3], float C[3][3]) {
#pragma clang fp contract(off)
    for (int i=0;i<3;i++)
        for (int j=0;j<3;j++) {
            float acc = A[i][0]*B[0][j];
            acc = acc + A[i][1]*B[1][j];
            acc = acc + A[i][2]*B[2][j];
            C[i][j] = acc;
        }
}
__device__ __forceinline__ void mm3_fma(const float A[3][3], const float B[3][3], float C[3][3]) {
#pragma clang fp contract(off)
    for (int i=0;i<3;i++)
        for (int j=0;j<3;j++) {
            float acc = A[i][0]*B[0][j];
            acc = __builtin_fmaf(A[i][1], B[1][j], acc);
            acc = __builtin_fmaf(A[i][2], B[2][j], acc);
            C[i][j] = acc;
        }
}
__device__ __forceinline__ float einsum_row(const float Fi[3], float x, float y) {
#pragma clang fp contract(off)
    float acc = Fi[0]*x;
    acc = acc + Fi[1]*y;
    acc = acc + Fi[2]*1.0f;
    return acc;
}

// ===== R30: R28 loop restored + __launch_bounds__(256,8) for full residency =====
// Occupancy math: grid = 1280 blocks x 4 waves = 5 waves/SIMD needed.
// waves/SIMD caps: 8 if VGPR<=64, 4 if <=128 (m69). R28 likely sat in the
// 65-128 band -> only 4 blocks/CU resident, 5th round serialized at 1
// block/CU (latency-exposed). Forcing <=64 VGPR makes the WHOLE grid
// co-resident in one round. R29's offs/live arrays (~60 VGPRs) reverted —
// its explicit pipeline was neutral (compiler already rotates loads).
// Hot loop needs ~50 VGPRs; only the one-time geometry prologue may spill.

__global__ __launch_bounds__(256, 8) void one2many_fused(
    const float* __restrict__ q, const float* __restrict__ k, const float* __restrict__ v,
    const float* __restrict__ K0, const float* __restrict__ K1,
    const float* __restrict__ R, const float* __restrict__ t,
    float* __restrict__ out)
{
#pragma clang fp contract(off)
    __shared__ int s_cand[CMAX];
    __shared__ int s_cnt;

    const int bx  = blockIdx.x;
    const int l   = (bx >> 3) + (bx & 7) * 160;   // XCD-contiguous bijection on [0,1280)
    const int tid = threadIdx.x;

    if (tid == 0) s_cnt = 0;

    const int w    = tid >> 6;          // wave index 0..3
    const int h0   = w;                 // first head
    const int h1   = w + 4;             // second head
    const int lane = tid & 63;
    const int grp  = lane >> 3;         // candidate sub-index within 8-group
    const int dj   = (lane & 7) << 2;   // dim offset 0,4,...,28

    // broadcast q loads: independent of geometry/scan -> issue early
    const float4 q4a = *(const float4*)(q + l*FEAT + h0*HEAD_DIM + dj);
    const float4 q4b = *(const float4*)(q + l*FEAT + h1*HEAD_DIM + dj);

    // ---- geometry: locked bit-exact chain, all threads, register-resident ----
    float slope, icpt; bool mode;
    {
        float i0[3][3], i1[3][3], A[3][3], B[3][3], T1[3][3], T2[3][3], Fm[3][3], Rm[3][3];
        np_inv3x3_reg(K0, i0);
        np_inv3x3_reg(K1, i1);
        for (int i=0;i<3;i++)
            for (int j=0;j<3;j++) { A[i][j] = i1[j][i]; Rm[i][j] = R[i*3+j]; }
        const float t0=t[0], t1=t[1], t2=t[2];
        B[0][0]=0.f;  B[0][1]=-t2;  B[0][2]=t1;
        B[1][0]=t2;   B[1][1]=0.f;  B[1][2]=-t0;
        B[2][0]=-t1;  B[2][1]=t0;   B[2][2]=0.f;
        mm3_chain(A,B,T1);      // noblas (swapaxes view)
        mm3_chain(T1,Rm,T2);    // T1 @ I
        mm3_fma(T2,i0,Fm);      // sgemm FMA
        const float xl = (float)(l % IMG_W);
        const float yl = (float)(l / IMG_W);
        const float la = einsum_row(Fm[0], xl, yl);
        const float lb = einsum_row(Fm[1], xl, yl);
        const float lc = einsum_row(Fm[2], xl, yl);
        mode = fabsf(lb) > fabsf(la);
        const float denom = mode ? lb : la;
        slope = (mode ? -la : -lb) / denom;
        icpt  = (-lc) / denom;
    }

    __syncthreads();   // s_cnt=0 visible

    // ---- candidate collection: identical fp32 band test ----
    for (int m = tid; m < NPIX; m += 256) {
        const float xm = (float)(m % IMG_W), ym = (float)(m / IMG_W);
        const float tin  = mode ? xm : ym;
        const float tchk = mode ? ym : xm;
        const float mu = slope * tin;
        const float cc = mu + icpt;
        const float hi = cc + 2.0f;
        const float lo = cc - 2.0f;
        if ((tchk < hi) && (tchk > lo) && m != 0) {
            int pos = atomicAdd(&s_cnt, 1);
            if (pos < CMAX) s_cand[pos] = m;
        }
    }
    __syncthreads();
    const int nc = min(s_cnt, CMAX);

    const float* kh0 = k + h0*HEAD_DIM + dj;
    const float* vh0 = v + h0*HEAD_DIM + dj;
    const float* kh1 = k + h1*HEAD_DIM + dj;
    const float* vh1 = v + h1*HEAD_DIM + dj;

    // ---- single-pass QK+softmax+AV for BOTH heads (no max subtraction) ----
    float ax0=0.f, ay0=0.f, az0=0.f, aw0=0.f, ps0=0.f;
    float ax1=0.f, ay1=0.f, az1=0.f, aw1=0.f, ps1=0.f;
    #pragma unroll
    for (int i = 0; i < NITER; i++) {
        const int ci  = (i << 3) + grp;
        const int row = s_cand[(ci < nc) ? ci : 0];
        const size_t off = (size_t)row * FEAT;
        const float4 k0 = *(const float4*)(kh0 + off);
        const float4 v0 = *(const float4*)(vh0 + off);
        const float4 k1 = *(const float4*)(kh1 + off);
        const float4 v1 = *(const float4*)(vh1 + off);

        float p0 = q4a.x*k0.x;
        p0 = __builtin_fmaf(q4a.y, k0.y, p0);
        p0 = __builtin_fmaf(q4a.z, k0.z, p0);
        p0 = __builtin_fmaf(q4a.w, k0.w, p0);
        p0 += __shfl_xor(p0, 1);
        p0 += __shfl_xor(p0, 2);
        p0 += __shfl_xor(p0, 4);            // full dot, identical across 8-group

        float p1 = q4b.x*k1.x;
        p1 = __builtin_fmaf(q4b.y, k1.y, p1);
        p1 = __builtin_fmaf(q4b.z, k1.z, p1);
        p1 = __builtin_fmaf(q4b.w, k1.w, p1);
        p1 += __shfl_xor(p1, 1);
        p1 += __shfl_xor(p1, 2);
        p1 += __shfl_xor(p1, 4);

        const bool live = (ci < nc);
        const float e0 = live ? __expf(p0 * 0.17677669529663687f) : 0.0f;
        const float e1 = live ? __expf(p1 * 0.17677669529663687f) : 0.0f;
        ps0 += e0;
        ax0 = __builtin_fmaf(e0, v0.x, ax0);
        ay0 = __builtin_fmaf(e0, v0.y, ay0);
        az0 = __builtin_fmaf(e0, v0.z, az0);
        aw0 = __builtin_fmaf(e0, v0.w, aw0);
        ps1 += e1;
        ax1 = __builtin_fmaf(e1, v1.x, ax1);
        ay1 = __builtin_fmaf(e1, v1.y, ay1);
        az1 = __builtin_fmaf(e1, v1.z, az1);
        aw1 = __builtin_fmaf(e1, v1.w, aw1);
    }

    // ---- reduce over the 8 candidate groups (bits 3..5 of lane) ----
    #pragma unroll
    for (int o = 8; o <= 32; o <<= 1) {
        ax0 += __shfl_xor(ax0, o);
        ay0 += __shfl_xor(ay0, o);
        az0 += __shfl_xor(az0, o);
        aw0 += __shfl_xor(aw0, o);
        ps0 += __shfl_xor(ps0, o);
        ax1 += __shfl_xor(ax1, o);
        ay1 += __shfl_xor(ay1, o);
        az1 += __shfl_xor(az1, o);
        aw1 += __shfl_xor(aw1, o);
        ps1 += __shfl_xor(ps1, o);
    }

    if (lane < 8) {
        float4 r0, r1;
        if (nc > 0) {
            r0.x = ax0/ps0; r0.y = ay0/ps0; r0.z = az0/ps0; r0.w = aw0/ps0;
            r1.x = ax1/ps1; r1.y = ay1/ps1; r1.z = az1/ps1; r1.w = aw1/ps1;
        } else {
            r0.x = r0.y = r0.z = r0.w = 0.0f;
            r1.x = r1.y = r1.z = r1.w = 0.0f;
        }
        *(float4*)(out + l*FEAT + h0*HEAD_DIM + dj) = r0;
        *(float4*)(out + l*FEAT + h1*HEAD_DIM + dj) = r1;
    }
}

extern "C" void kernel_launch(void* const* d_in, const int* in_sizes, int n_in,
                              void* d_out, int out_size, void* d_ws, size_t ws_size,
                              hipStream_t stream) {
    const float* q  = (const float*)d_in[0];
    const float* k  = (const float*)d_in[1];
    const float* v  = (const float*)d_in[2];
    const float* K0 = (const float*)d_in[3];
    const float* K1 = (const float*)d_in[4];
    const float* R  = (const float*)d_in[5];
    const float* t  = (const float*)d_in[6];
    float* out = (float*)d_out;
    (void)d_ws; (void)ws_size;
    one2many_fused<<<NPIX, 256, 0, stream>>>(q, k, v, K0, K1, R, t, out);
}

// Round 10
// 102.715 us; speedup vs baseline: 1.3098x; 1.3098x over previous
//
#include <hip/hip_runtime.h>
#include <math.h>

#define NHEAD 8
#define HEAD_DIM 32
#define IMG_H 32
#define IMG_W 40
#define NPIX (IMG_H*IMG_W)
#define CMAX 160
#define NITER (CMAX/8)   // 20
#define FEAT (NHEAD*HEAD_DIM)

// ===== Geometry: LOCKED bit-exact numpy-fp32 emulation =====
// R27: register-LU (explicit scalars + pivot selects, arithmetic 1:1 with
// numpy chain) -> fusable without scratch demotion. PASSED, absmax 2^-10.

__device__ __forceinline__ void np_inv3x3_reg(const float* __restrict__ M, float inv[3][3]) {
#pragma clang fp contract(off)
    float a00=M[0], a01=M[1], a02=M[2];
    float a10=M[3], a11=M[4], a12=M[5];
    float a20=M[6], a21=M[7], a22=M[8];

    // ---- kk=0: pivot search (strictly-greater update, as numpy) ----
    const float c0 = fabsf(a00), c1 = fabsf(a10), c2 = fabsf(a20);
    const bool s1 = c1 > c0;
    const float cm = s1 ? c1 : c0;
    const bool s2 = c2 > cm;
    const bool q1 = s1 && !s2;      // pivot row 1
    const bool q2 = s2;             // pivot row 2 (q1,q2 mutually exclusive)
    {   // full row swap 0 <-> p0
        const float n0 = q2 ? a20 : (q1 ? a10 : a00);
        const float n1 = q2 ? a21 : (q1 ? a11 : a01);
        const float n2 = q2 ? a22 : (q1 ? a12 : a02);
        const float m0 = q1 ? a00 : a10, m1 = q1 ? a01 : a11, m2 = q1 ? a02 : a12;
        const float r0 = q2 ? a00 : a20, r1 = q2 ? a01 : a21, r2 = q2 ? a02 : a22;
        a00=n0; a01=n1; a02=n2;
        a10=m0; a11=m1; a12=m2;
        a20=r0; a21=r1; a22=r2;
    }
    const float rp0 = 1.0f / a00;
    a10 = a10 * rp0;
    a20 = a20 * rp0;
    a11 = a11 - a10*a01;
    a12 = a12 - a10*a02;
    a21 = a21 - a20*a01;
    a22 = a22 - a20*a02;

    // ---- kk=1: pivot search over rows 1,2 ----
    const bool sB = fabsf(a21) > fabsf(a11);
    {   // full row swap 1 <-> 2 (includes factored column 0, as numpy)
        const float t0 = sB ? a20 : a10, t1 = sB ? a21 : a11, t2 = sB ? a22 : a12;
        const float u0 = sB ? a10 : a20, u1 = sB ? a11 : a21, u2 = sB ? a12 : a22;
        a10=t0; a11=t1; a12=t2;
        a20=u0; a21=u1; a22=u2;
    }
    const float rp1 = 1.0f / a11;
    a21 = a21 * rp1;
    a22 = a22 - a21*a12;
    // kk=2: pivot is row 2, no swap, no elimination.

    // ---- solve A x = e_col for col=0,1,2 (constant-trip, unrolled) ----
    #pragma unroll
    for (int col = 0; col < 3; col++) {
        float b0 = (col==0) ? 1.0f : 0.0f;
        float b1 = (col==1) ? 1.0f : 0.0f;
        float b2 = (col==2) ? 1.0f : 0.0f;
        {   // apply piv[0]
            const float w0 = q2 ? b2 : (q1 ? b1 : b0);
            const float w1 = q1 ? b0 : b1;
            const float w2 = q2 ? b0 : b2;
            b0=w0; b1=w1; b2=w2;
        }
        {   // apply piv[1]
            const float x1 = sB ? b2 : b1;
            const float x2 = sB ? b1 : b2;
            b1=x1; b2=x2;
        }
        // forward substitution (i=1:kk=0; i=2:kk=0,1)
        b1 = b1 - a10*b0;
        b2 = b2 - a20*b0;
        b2 = b2 - a21*b1;
        // back substitution (kk=2: i=0,1; kk=1: i=0; kk=0)
        b2 = b2 / a22;
        b0 = b0 - a02*b2;
        b1 = b1 - a12*b2;
        b1 = b1 / a11;
        b0 = b0 - a01*b1;
        b0 = b0 / a00;
        inv[0][col]=b0; inv[1][col]=b1; inv[2][col]=b2;
    }
}

__device__ __forceinline__ void mm3_chain(const float A[3][3], const float B[3][3], float C[3][3]) {
#pragma clang fp contract(off)
    for (int i=0;i<3;i++)
        for (int j=0;j<3;j++) {
            float acc = A[i][0]*B[0][j];
            acc = acc + A[i][1]*B[1][j];
            acc = acc + A[i][2]*B[2][j];
            C[i][j] = acc;
        }
}
__device__ __forceinline__ void mm3_fma(const float A[3][3], const float B[3][3], float C[3][3]) {
#pragma clang fp contract(off)
    for (int i=0;i<3;i++)
        for (int j=0;j<3;j++) {
            float acc = A[i][0]*B[0][j];
            acc = __builtin_fmaf(A[i][1], B[1][j], acc);
            acc = __builtin_fmaf(A[i][2], B[2][j], acc);
            C[i][j] = acc;
        }
}
__device__ __forceinline__ float einsum_row(const float Fi[3], float x, float y) {
#pragma clang fp contract(off)
    float acc = Fi[0]*x;
    acc = acc + Fi[1]*y;
    acc = acc + Fi[2]*1.0f;
    return acc;
}

// ===== R31: 128-thread blocks (2 waves), wave owns FOUR heads =====
// R30 lesson: launch_bounds(256,8) forced VGPR=32 -> ~230 MB scratch
// traffic/dispatch (FETCH 82 MB, WRITE 143 MB), kernel 28->70+ us. NEVER
// force occupancy past the register budget. Correct fix for the straggler
// round: HW gives 4 waves/SIMD at VGPR<=128. With 2-wave blocks that is
// 8 blocks/CU >= the 5 blocks/CU the 1280-block grid needs -> WHOLE grid
// co-resident in one round (256-thread blocks topped out at 4 blocks/CU).
// Wave w handles heads w*4..w*4+3: 8 independent gathers/iter (2x MLP).
// launch_bounds(128,4) = gentle VGPR<=128 cap; hot loop needs ~100.

__global__ __launch_bounds__(128, 4) void one2many_fused(
    const float* __restrict__ q, const float* __restrict__ k, const float* __restrict__ v,
    const float* __restrict__ K0, const float* __restrict__ K1,
    const float* __restrict__ R, const float* __restrict__ t,
    float* __restrict__ out)
{
#pragma clang fp contract(off)
    __shared__ int s_cand[CMAX];
    __shared__ int s_cnt;

    const int bx  = blockIdx.x;
    const int l   = (bx >> 3) + (bx & 7) * 160;   // XCD-contiguous bijection on [0,1280)
    const int tid = threadIdx.x;

    if (tid == 0) s_cnt = 0;

    const int w    = tid >> 6;          // wave index 0..1
    const int hb   = w << 2;            // head base: 0 or 4
    const int lane = tid & 63;
    const int grp  = lane >> 3;         // candidate sub-index within 8-group
    const int dj   = (lane & 7) << 2;   // dim offset 0,4,...,28

    // q loads: independent of geometry/scan -> issue early
    float4 q4[4];
    #pragma unroll
    for (int j = 0; j < 4; j++)
        q4[j] = *(const float4*)(q + l*FEAT + (hb+j)*HEAD_DIM + dj);

    // ---- geometry: locked bit-exact chain, all threads, register-resident ----
    float slope, icpt; bool mode;
    {
        float i0[3][3], i1[3][3], A[3][3], B[3][3], T1[3][3], T2[3][3], Fm[3][3], Rm[3][3];
        np_inv3x3_reg(K0, i0);
        np_inv3x3_reg(K1, i1);
        for (int i=0;i<3;i++)
            for (int j=0;j<3;j++) { A[i][j] = i1[j][i]; Rm[i][j] = R[i*3+j]; }
        const float t0=t[0], t1=t[1], t2=t[2];
        B[0][0]=0.f;  B[0][1]=-t2;  B[0][2]=t1;
        B[1][0]=t2;   B[1][1]=0.f;  B[1][2]=-t0;
        B[2][0]=-t1;  B[2][1]=t0;   B[2][2]=0.f;
        mm3_chain(A,B,T1);      // noblas (swapaxes view)
        mm3_chain(T1,Rm,T2);    // T1 @ I
        mm3_fma(T2,i0,Fm);      // sgemm FMA
        const float xl = (float)(l % IMG_W);
        const float yl = (float)(l / IMG_W);
        const float la = einsum_row(Fm[0], xl, yl);
        const float lb = einsum_row(Fm[1], xl, yl);
        const float lc = einsum_row(Fm[2], xl, yl);
        mode = fabsf(lb) > fabsf(la);
        const float denom = mode ? lb : la;
        slope = (mode ? -la : -lb) / denom;
        icpt  = (-lc) / denom;
    }

    __syncthreads();   // s_cnt=0 visible

    // ---- candidate collection: identical fp32 band test ----
    for (int m = tid; m < NPIX; m += 128) {
        const float xm = (float)(m % IMG_W), ym = (float)(m / IMG_W);
        const float tin  = mode ? xm : ym;
        const float tchk = mode ? ym : xm;
        const float mu = slope * tin;
        const float cc = mu + icpt;
        const float hi = cc + 2.0f;
        const float lo = cc - 2.0f;
        if ((tchk < hi) && (tchk > lo) && m != 0) {
            int pos = atomicAdd(&s_cnt, 1);
            if (pos < CMAX) s_cand[pos] = m;
        }
    }
    __syncthreads();
    const int nc = min(s_cnt, CMAX);

    const float* kbase = k + hb*HEAD_DIM + dj;
    const float* vbase = v + hb*HEAD_DIM + dj;

    // ---- single-pass QK+softmax+AV for FOUR heads (no max subtraction) ----
    float ax[4], ay[4], az[4], aw[4], ps[4];
    #pragma unroll
    for (int j = 0; j < 4; j++) { ax[j]=0.f; ay[j]=0.f; az[j]=0.f; aw[j]=0.f; ps[j]=0.f; }

    #pragma unroll
    for (int i = 0; i < NITER; i++) {
        const int ci  = (i << 3) + grp;
        const int row = s_cand[(ci < nc) ? ci : 0];
        const size_t off = (size_t)row * FEAT;
        const bool live = (ci < nc);

        // issue all 8 loads first (max MLP), then compute
        float4 k4[4], v4[4];
        #pragma unroll
        for (int j = 0; j < 4; j++) {
            k4[j] = *(const float4*)(kbase + off + j*HEAD_DIM);
            v4[j] = *(const float4*)(vbase + off + j*HEAD_DIM);
        }

        #pragma unroll
        for (int j = 0; j < 4; j++) {
            float p = q4[j].x*k4[j].x;
            p = __builtin_fmaf(q4[j].y, k4[j].y, p);
            p = __builtin_fmaf(q4[j].z, k4[j].z, p);
            p = __builtin_fmaf(q4[j].w, k4[j].w, p);
            p += __shfl_xor(p, 1);
            p += __shfl_xor(p, 2);
            p += __shfl_xor(p, 4);          // full dot, identical across 8-group
            const float e = live ? __expf(p * 0.17677669529663687f) : 0.0f;
            ps[j] += e;
            ax[j] = __builtin_fmaf(e, v4[j].x, ax[j]);
            ay[j] = __builtin_fmaf(e, v4[j].y, ay[j]);
            az[j] = __builtin_fmaf(e, v4[j].z, az[j]);
            aw[j] = __builtin_fmaf(e, v4[j].w, aw[j]);
        }
    }

    // ---- reduce over the 8 candidate groups (bits 3..5 of lane) ----
    #pragma unroll
    for (int o = 8; o <= 32; o <<= 1) {
        #pragma unroll
        for (int j = 0; j < 4; j++) {
            ax[j] += __shfl_xor(ax[j], o);
            ay[j] += __shfl_xor(ay[j], o);
            az[j] += __shfl_xor(az[j], o);
            aw[j] += __shfl_xor(aw[j], o);
            ps[j] += __shfl_xor(ps[j], o);
        }
    }

    if (lane < 8) {
        #pragma unroll
        for (int j = 0; j < 4; j++) {
            float4 r;
            if (nc > 0) { r.x = ax[j]/ps[j]; r.y = ay[j]/ps[j]; r.z = az[j]/ps[j]; r.w = aw[j]/ps[j]; }
            else        { r.x = r.y = r.z = r.w = 0.0f; }
            *(float4*)(out + l*FEAT + (hb+j)*HEAD_DIM + dj) = r;
        }
    }
}

extern "C" void kernel_launch(void* const* d_in, const int* in_sizes, int n_in,
                              void* d_out, int out_size, void* d_ws, size_t ws_size,
                              hipStream_t stream) {
    const float* q  = (const float*)d_in[0];
    const float* k  = (const float*)d_in[1];
    const float* v  = (const float*)d_in[2];
    const float* K0 = (const float*)d_in[3];
    const float* K1 = (const float*)d_in[4];
    const float* R  = (const float*)d_in[5];
    const float* t  = (const float*)d_in[6];
    float* out = (float*)d_out;
    (void)d_ws; (void)ws_size;
    one2many_fused<<<NPIX, 128, 0, stream>>>(q, k, v, K0, K1, R, t, out);
}

// Round 11
// 93.388 us; speedup vs baseline: 1.4406x; 1.0999x over previous
//
#include <hip/hip_runtime.h>
#include <math.h>

#define NHEAD 8
#define HEAD_DIM 32
#define IMG_H 32
#define IMG_W 40
#define NPIX (IMG_H*IMG_W)
#define CMAX 160
#define NITER (CMAX/8)   // 20
#define FEAT (NHEAD*HEAD_DIM)

// ===== Geometry: LOCKED bit-exact numpy-fp32 emulation =====
// R27: register-LU (explicit scalars + pivot selects, arithmetic 1:1 with
// numpy chain) -> fusable without scratch demotion. PASSED, absmax 2^-10.

__device__ __forceinline__ void np_inv3x3_reg(const float* __restrict__ M, float inv[3][3]) {
#pragma clang fp contract(off)
    float a00=M[0], a01=M[1], a02=M[2];
    float a10=M[3], a11=M[4], a12=M[5];
    float a20=M[6], a21=M[7], a22=M[8];

    // ---- kk=0: pivot search (strictly-greater update, as numpy) ----
    const float c0 = fabsf(a00), c1 = fabsf(a10), c2 = fabsf(a20);
    const bool s1 = c1 > c0;
    const float cm = s1 ? c1 : c0;
    const bool s2 = c2 > cm;
    const bool q1 = s1 && !s2;      // pivot row 1
    const bool q2 = s2;             // pivot row 2 (q1,q2 mutually exclusive)
    {   // full row swap 0 <-> p0
        const float n0 = q2 ? a20 : (q1 ? a10 : a00);
        const float n1 = q2 ? a21 : (q1 ? a11 : a01);
        const float n2 = q2 ? a22 : (q1 ? a12 : a02);
        const float m0 = q1 ? a00 : a10, m1 = q1 ? a01 : a11, m2 = q1 ? a02 : a12;
        const float r0 = q2 ? a00 : a20, r1 = q2 ? a01 : a21, r2 = q2 ? a02 : a22;
        a00=n0; a01=n1; a02=n2;
        a10=m0; a11=m1; a12=m2;
        a20=r0; a21=r1; a22=r2;
    }
    const float rp0 = 1.0f / a00;
    a10 = a10 * rp0;
    a20 = a20 * rp0;
    a11 = a11 - a10*a01;
    a12 = a12 - a10*a02;
    a21 = a21 - a20*a01;
    a22 = a22 - a20*a02;

    // ---- kk=1: pivot search over rows 1,2 ----
    const bool sB = fabsf(a21) > fabsf(a11);
    {   // full row swap 1 <-> 2 (includes factored column 0, as numpy)
        const float t0 = sB ? a20 : a10, t1 = sB ? a21 : a11, t2 = sB ? a22 : a12;
        const float u0 = sB ? a10 : a20, u1 = sB ? a11 : a21, u2 = sB ? a12 : a22;
        a10=t0; a11=t1; a12=t2;
        a20=u0; a21=u1; a22=u2;
    }
    const float rp1 = 1.0f / a11;
    a21 = a21 * rp1;
    a22 = a22 - a21*a12;
    // kk=2: pivot is row 2, no swap, no elimination.

    // ---- solve A x = e_col for col=0,1,2 (constant-trip, unrolled) ----
    #pragma unroll
    for (int col = 0; col < 3; col++) {
        float b0 = (col==0) ? 1.0f : 0.0f;
        float b1 = (col==1) ? 1.0f : 0.0f;
        float b2 = (col==2) ? 1.0f : 0.0f;
        {   // apply piv[0]
            const float w0 = q2 ? b2 : (q1 ? b1 : b0);
            const float w1 = q1 ? b0 : b1;
            const float w2 = q2 ? b0 : b2;
            b0=w0; b1=w1; b2=w2;
        }
        {   // apply piv[1]
            const float x1 = sB ? b2 : b1;
            const float x2 = sB ? b1 : b2;
            b1=x1; b2=x2;
        }
        // forward substitution (i=1:kk=0; i=2:kk=0,1)
        b1 = b1 - a10*b0;
        b2 = b2 - a20*b0;
        b2 = b2 - a21*b1;
        // back substitution (kk=2: i=0,1; kk=1: i=0; kk=0)
        b2 = b2 / a22;
        b0 = b0 - a02*b2;
        b1 = b1 - a12*b2;
        b1 = b1 / a11;
        b0 = b0 - a01*b1;
        b0 = b0 / a00;
        inv[0][col]=b0; inv[1][col]=b1; inv[2][col]=b2;
    }
}

__device__ __forceinline__ void mm3_chain(const float A[3][3], const float B[3][3], float C[3][3]) {
#pragma clang fp contract(off)
    for (int i=0;i<3;i++)
        for (int j=0;j<3;j++) {
            float acc = A[i][0]*B[0][j];
            acc = acc + A[i][1]*B[1][j];
            acc = acc + A[i][2]*B[2][j];
            C[i][j] = acc;
        }
}
__device__ __forceinline__ void mm3_fma(const float A[3][3], const float B[3][3], float C[3][3]) {
#pragma clang fp contract(off)
    for (int i=0;i<3;i++)
        for (int j=0;j<3;j++) {
            float acc = A[i][0]*B[0][j];
            acc = __builtin_fmaf(A[i][1], B[1][j], acc);
            acc = __builtin_fmaf(A[i][2], B[2][j], acc);
            C[i][j] = acc;
        }
}
__device__ __forceinline__ float einsum_row(const float Fi[3], float x, float y) {
#pragma clang fp contract(off)
    float acc = Fi[0]*x;
    acc = acc + Fi[1]*y;
    acc = acc + Fi[2]*1.0f;
    return acc;
}

// ===== R32: R31 shape with UNCONSTRAINED allocator =====
// R30/R31 lesson (two data points): hipcc's launch_bounds arg2 maps to a
// VGPR cap of 512/(2*arg2) — (256,8)->32, (128,4)->64 — both ~36 regs
// below the ~100-VGPR hot loop -> forced scratch spill (R31: 38 MB/dispatch
// scratch traffic, kernel 42 us). NEVER pass arg2 on this toolchain.
// The 128-thread/2-wave/4-heads-per-wave shape itself is sound: at the
// natural VGPR (~100-120 <= 128) the HW runs 4 waves/SIMD = 8 blocks/CU
// >= the 5 blocks/CU the 1280-block grid needs -> whole grid co-resident
// in ONE round (R28's 256-thread blocks capped at 4 blocks/CU -> straggler
// round), with 8 independent gathers/iter/wave.

__global__ __launch_bounds__(128) void one2many_fused(
    const float* __restrict__ q, const float* __restrict__ k, const float* __restrict__ v,
    const float* __restrict__ K0, const float* __restrict__ K1,
    const float* __restrict__ R, const float* __restrict__ t,
    float* __restrict__ out)
{
#pragma clang fp contract(off)
    __shared__ int s_cand[CMAX];
    __shared__ int s_cnt;

    const int bx  = blockIdx.x;
    const int l   = (bx >> 3) + (bx & 7) * 160;   // XCD-contiguous bijection on [0,1280)
    const int tid = threadIdx.x;

    if (tid == 0) s_cnt = 0;

    const int w    = tid >> 6;          // wave index 0..1
    const int hb   = w << 2;            // head base: 0 or 4
    const int lane = tid & 63;
    const int grp  = lane >> 3;         // candidate sub-index within 8-group
    const int dj   = (lane & 7) << 2;   // dim offset 0,4,...,28

    // q loads: independent of geometry/scan -> issue early
    float4 q4[4];
    #pragma unroll
    for (int j = 0; j < 4; j++)
        q4[j] = *(const float4*)(q + l*FEAT + (hb+j)*HEAD_DIM + dj);

    // ---- geometry: locked bit-exact chain, all threads, register-resident ----
    float slope, icpt; bool mode;
    {
        float i0[3][3], i1[3][3], A[3][3], B[3][3], T1[3][3], T2[3][3], Fm[3][3], Rm[3][3];
        np_inv3x3_reg(K0, i0);
        np_inv3x3_reg(K1, i1);
        for (int i=0;i<3;i++)
            for (int j=0;j<3;j++) { A[i][j] = i1[j][i]; Rm[i][j] = R[i*3+j]; }
        const float t0=t[0], t1=t[1], t2=t[2];
        B[0][0]=0.f;  B[0][1]=-t2;  B[0][2]=t1;
        B[1][0]=t2;   B[1][1]=0.f;  B[1][2]=-t0;
        B[2][0]=-t1;  B[2][1]=t0;   B[2][2]=0.f;
        mm3_chain(A,B,T1);      // noblas (swapaxes view)
        mm3_chain(T1,Rm,T2);    // T1 @ I
        mm3_fma(T2,i0,Fm);      // sgemm FMA
        const float xl = (float)(l % IMG_W);
        const float yl = (float)(l / IMG_W);
        const float la = einsum_row(Fm[0], xl, yl);
        const float lb = einsum_row(Fm[1], xl, yl);
        const float lc = einsum_row(Fm[2], xl, yl);
        mode = fabsf(lb) > fabsf(la);
        const float denom = mode ? lb : la;
        slope = (mode ? -la : -lb) / denom;
        icpt  = (-lc) / denom;
    }

    __syncthreads();   // s_cnt=0 visible

    // ---- candidate collection: identical fp32 band test ----
    for (int m = tid; m < NPIX; m += 128) {
        const float xm = (float)(m % IMG_W), ym = (float)(m / IMG_W);
        const float tin  = mode ? xm : ym;
        const float tchk = mode ? ym : xm;
        const float mu = slope * tin;
        const float cc = mu + icpt;
        const float hi = cc + 2.0f;
        const float lo = cc - 2.0f;
        if ((tchk < hi) && (tchk > lo) && m != 0) {
            int pos = atomicAdd(&s_cnt, 1);
            if (pos < CMAX) s_cand[pos] = m;
        }
    }
    __syncthreads();
    const int nc = min(s_cnt, CMAX);

    const float* kbase = k + hb*HEAD_DIM + dj;
    const float* vbase = v + hb*HEAD_DIM + dj;

    // ---- single-pass QK+softmax+AV for FOUR heads (no max subtraction) ----
    float ax[4], ay[4], az[4], aw[4], ps[4];
    #pragma unroll
    for (int j = 0; j < 4; j++) { ax[j]=0.f; ay[j]=0.f; az[j]=0.f; aw[j]=0.f; ps[j]=0.f; }

    #pragma unroll
    for (int i = 0; i < NITER; i++) {
        const int ci  = (i << 3) + grp;
        const int row = s_cand[(ci < nc) ? ci : 0];
        const size_t off = (size_t)row * FEAT;
        const bool live = (ci < nc);

        // issue all 8 loads first (max MLP), then compute
        float4 k4[4], v4[4];
        #pragma unroll
        for (int j = 0; j < 4; j++) {
            k4[j] = *(const float4*)(kbase + off + j*HEAD_DIM);
            v4[j] = *(const float4*)(vbase + off + j*HEAD_DIM);
        }

        #pragma unroll
        for (int j = 0; j < 4; j++) {
            float p = q4[j].x*k4[j].x;
            p = __builtin_fmaf(q4[j].y, k4[j].y, p);
            p = __builtin_fmaf(q4[j].z, k4[j].z, p);
            p = __builtin_fmaf(q4[j].w, k4[j].w, p);
            p += __shfl_xor(p, 1);
            p += __shfl_xor(p, 2);
            p += __shfl_xor(p, 4);          // full dot, identical across 8-group
            const float e = live ? __expf(p * 0.17677669529663687f) : 0.0f;
            ps[j] += e;
            ax[j] = __builtin_fmaf(e, v4[j].x, ax[j]);
            ay[j] = __builtin_fmaf(e, v4[j].y, ay[j]);
            az[j] = __builtin_fmaf(e, v4[j].z, az[j]);
            aw[j] = __builtin_fmaf(e, v4[j].w, aw[j]);
        }
    }

    // ---- reduce over the 8 candidate groups (bits 3..5 of lane) ----
    #pragma unroll
    for (int o = 8; o <= 32; o <<= 1) {
        #pragma unroll
        for (int j = 0; j < 4; j++) {
            ax[j] += __shfl_xor(ax[j], o);
            ay[j] += __shfl_xor(ay[j], o);
            az[j] += __shfl_xor(az[j], o);
            aw[j] += __shfl_xor(aw[j], o);
            ps[j] += __shfl_xor(ps[j], o);
        }
    }

    if (lane < 8) {
        #pragma unroll
        for (int j = 0; j < 4; j++) {
            float4 r;
            if (nc > 0) { r.x = ax[j]/ps[j]; r.y = ay[j]/ps[j]; r.z = az[j]/ps[j]; r.w = aw[j]/ps[j]; }
            else        { r.x = r.y = r.z = r.w = 0.0f; }
            *(float4*)(out + l*FEAT + (hb+j)*HEAD_DIM + dj) = r;
        }
    }
}

extern "C" void kernel_launch(void* const* d_in, const int* in_sizes, int n_in,
                              void* d_out, int out_size, void* d_ws, size_t ws_size,
                              hipStream_t stream) {
    const float* q  = (const float*)d_in[0];
    const float* k  = (const float*)d_in[1];
    const float* v  = (const float*)d_in[2];
    const float* K0 = (const float*)d_in[3];
    const float* K1 = (const float*)d_in[4];
    const float* R  = (const float*)d_in[5];
    const float* t  = (const float*)d_in[6];
    float* out = (float*)d_out;
    (void)d_ws; (void)ws_size;
    one2many_fused<<<NPIX, 128, 0, stream>>>(q, k, v, K0, K1, R, t, out);
}

// Round 12
// 83.372 us; speedup vs baseline: 1.6136x; 1.1201x over previous
//
#include <hip/hip_runtime.h>
#include <math.h>

#define NHEAD 8
#define HEAD_DIM 32
#define IMG_H 32
#define IMG_W 40
#define NPIX (IMG_H*IMG_W)
#define CMAX 160
#define CPW (CMAX/4)     // 40 candidates per wave
#define FEAT (NHEAD*HEAD_DIM)

// ===== Geometry: LOCKED bit-exact numpy-fp32 emulation =====
// R27: register-LU (explicit scalars + pivot selects, arithmetic 1:1 with
// numpy chain) -> fusable without scratch demotion. PASSED, absmax 2^-10.

__device__ __forceinline__ void np_inv3x3_reg(const float* __restrict__ M, float inv[3][3]) {
#pragma clang fp contract(off)
    float a00=M[0], a01=M[1], a02=M[2];
    float a10=M[3], a11=M[4], a12=M[5];
    float a20=M[6], a21=M[7], a22=M[8];

    // ---- kk=0: pivot search (strictly-greater update, as numpy) ----
    const float c0 = fabsf(a00), c1 = fabsf(a10), c2 = fabsf(a20);
    const bool s1 = c1 > c0;
    const float cm = s1 ? c1 : c0;
    const bool s2 = c2 > cm;
    const bool q1 = s1 && !s2;      // pivot row 1
    const bool q2 = s2;             // pivot row 2 (q1,q2 mutually exclusive)
    {   // full row swap 0 <-> p0
        const float n0 = q2 ? a20 : (q1 ? a10 : a00);
        const float n1 = q2 ? a21 : (q1 ? a11 : a01);
        const float n2 = q2 ? a22 : (q1 ? a12 : a02);
        const float m0 = q1 ? a00 : a10, m1 = q1 ? a01 : a11, m2 = q1 ? a02 : a12;
        const float r0 = q2 ? a00 : a20, r1 = q2 ? a01 : a21, r2 = q2 ? a02 : a22;
        a00=n0; a01=n1; a02=n2;
        a10=m0; a11=m1; a12=m2;
        a20=r0; a21=r1; a22=r2;
    }
    const float rp0 = 1.0f / a00;
    a10 = a10 * rp0;
    a20 = a20 * rp0;
    a11 = a11 - a10*a01;
    a12 = a12 - a10*a02;
    a21 = a21 - a20*a01;
    a22 = a22 - a20*a02;

    // ---- kk=1: pivot search over rows 1,2 ----
    const bool sB = fabsf(a21) > fabsf(a11);
    {   // full row swap 1 <-> 2 (includes factored column 0, as numpy)
        const float t0 = sB ? a20 : a10, t1 = sB ? a21 : a11, t2 = sB ? a22 : a12;
        const float u0 = sB ? a10 : a20, u1 = sB ? a11 : a21, u2 = sB ? a12 : a22;
        a10=t0; a11=t1; a12=t2;
        a20=u0; a21=u1; a22=u2;
    }
    const float rp1 = 1.0f / a11;
    a21 = a21 * rp1;
    a22 = a22 - a21*a12;
    // kk=2: pivot is row 2, no swap, no elimination.

    // ---- solve A x = e_col for col=0,1,2 (constant-trip, unrolled) ----
    #pragma unroll
    for (int col = 0; col < 3; col++) {
        float b0 = (col==0) ? 1.0f : 0.0f;
        float b1 = (col==1) ? 1.0f : 0.0f;
        float b2 = (col==2) ? 1.0f : 0.0f;
        {   // apply piv[0]
            const float w0 = q2 ? b2 : (q1 ? b1 : b0);
            const float w1 = q1 ? b0 : b1;
            const float w2 = q2 ? b0 : b2;
            b0=w0; b1=w1; b2=w2;
        }
        {   // apply piv[1]
            const float x1 = sB ? b2 : b1;
            const float x2 = sB ? b1 : b2;
            b1=x1; b2=x2;
        }
        // forward substitution (i=1:kk=0; i=2:kk=0,1)
        b1 = b1 - a10*b0;
        b2 = b2 - a20*b0;
        b2 = b2 - a21*b1;
        // back substitution (kk=2: i=0,1; kk=1: i=0; kk=0)
        b2 = b2 / a22;
        b0 = b0 - a02*b2;
        b1 = b1 - a12*b2;
        b1 = b1 / a11;
        b0 = b0 - a01*b1;
        b0 = b0 / a00;
        inv[0][col]=b0; inv[1][col]=b1; inv[2][col]=b2;
    }
}

__device__ __forceinline__ void mm3_chain(const float A[3][3], const float B[3][3], float C[3][3]) {
#pragma clang fp contract(off)
    for (int i=0;i<3;i++)
        for (int j=0;j<3;j++) {
            float acc = A[i][0]*B[0][j];
            acc = acc + A[i][1]*B[1][j];
            acc = acc + A[i][2]*B[2][j];
            C[i][j] = acc;
        }
}
__device__ __forceinline__ void mm3_fma(const float A[3][3], const float B[3][3], float C[3][3]) {
#pragma clang fp contract(off)
    for (int i=0;i<3;i++)
        for (int j=0;j<3;j++) {
            float acc = A[i][0]*B[0][j];
            acc = __builtin_fmaf(A[i][1], B[1][j], acc);
            acc = __builtin_fmaf(A[i][2], B[2][j], acc);
            C[i][j] = acc;
        }
}
__device__ __forceinline__ float einsum_row(const float Fi[3], float x, float y) {
#pragma clang fp contract(off)
    float acc = Fi[0]*x;
    acc = acc + Fi[1]*y;
    acc = acc + Fi[2]*1.0f;
    return acc;
}

// ===== R33: wave-uniform candidate -> fully-coalesced 1024-B gathers =====
// R28/R29/R32 triangulation: occupancy rounds & explicit pipelining are NOT
// the lever (R32 fully-resident yet 93.4 > R28's 86.2). Shared flaw: every
// gather instruction touched 8 scattered 128-B segments (8 candidate groups
// per wave) -> ~8 coalescer requests per load, ~42% L2 BW ceiling. New
// layout: lane = (head = lane>>3, dims = (lane&7)*4); ONE candidate per
// wave per iteration, index wave-uniform (readfirstlane -> SGPR base):
// K and V loads are single contiguous 1024-B requests, zero divergence,
// near-zero addr VALU. 4 waves split the 160 candidates (40 each);
// cross-wave combine via 5 KB LDS; wave 0 writes the full output row
// coalesced. Per-lane FMA/shfl/exp counts identical to R28. Masked-slot-0
// semantics verbatim. No launch_bounds arg2 (R30/R31 lesson).

__global__ __launch_bounds__(256) void one2many_fused(
    const float* __restrict__ q, const float* __restrict__ k, const float* __restrict__ v,
    const float* __restrict__ K0, const float* __restrict__ K1,
    const float* __restrict__ R, const float* __restrict__ t,
    float* __restrict__ out)
{
#pragma clang fp contract(off)
    __shared__ int s_cand[CMAX];
    __shared__ int s_cnt;
    __shared__ float s_ax[256], s_ay[256], s_az[256], s_aw[256], s_ps[256];

    const int bx  = blockIdx.x;
    const int l   = (bx >> 3) + (bx & 7) * 160;   // XCD-contiguous bijection on [0,1280)
    const int tid = threadIdx.x;

    if (tid == 0) s_cnt = 0;

    const int w    = tid >> 6;          // wave index 0..3
    const int lane = tid & 63;          // lane -> (head = lane>>3, dims = (lane&7)*4)

    // q: each lane holds its (head,dims) slice; wave covers the full row.
    const float4 q4 = *(const float4*)(q + l*FEAT + (lane << 2));

    // ---- geometry: locked bit-exact chain, all threads, register-resident ----
    float slope, icpt; bool mode;
    {
        float i0[3][3], i1[3][3], A[3][3], B[3][3], T1[3][3], T2[3][3], Fm[3][3], Rm[3][3];
        np_inv3x3_reg(K0, i0);
        np_inv3x3_reg(K1, i1);
        for (int i=0;i<3;i++)
            for (int j=0;j<3;j++) { A[i][j] = i1[j][i]; Rm[i][j] = R[i*3+j]; }
        const float t0=t[0], t1=t[1], t2=t[2];
        B[0][0]=0.f;  B[0][1]=-t2;  B[0][2]=t1;
        B[1][0]=t2;   B[1][1]=0.f;  B[1][2]=-t0;
        B[2][0]=-t1;  B[2][1]=t0;   B[2][2]=0.f;
        mm3_chain(A,B,T1);      // noblas (swapaxes view)
        mm3_chain(T1,Rm,T2);    // T1 @ I
        mm3_fma(T2,i0,Fm);      // sgemm FMA
        const float xl = (float)(l % IMG_W);
        const float yl = (float)(l / IMG_W);
        const float la = einsum_row(Fm[0], xl, yl);
        const float lb = einsum_row(Fm[1], xl, yl);
        const float lc = einsum_row(Fm[2], xl, yl);
        mode = fabsf(lb) > fabsf(la);
        const float denom = mode ? lb : la;
        slope = (mode ? -la : -lb) / denom;
        icpt  = (-lc) / denom;
    }

    __syncthreads();   // s_cnt=0 visible

    // ---- candidate collection: identical fp32 band test (stride 256 = R28) ----
    for (int m = tid; m < NPIX; m += 256) {
        const float xm = (float)(m % IMG_W), ym = (float)(m / IMG_W);
        const float tin  = mode ? xm : ym;
        const float tchk = mode ? ym : xm;
        const float mu = slope * tin;
        const float cc = mu + icpt;
        const float hi = cc + 2.0f;
        const float lo = cc - 2.0f;
        if ((tchk < hi) && (tchk > lo) && m != 0) {
            int pos = atomicAdd(&s_cnt, 1);
            if (pos < CMAX) s_cand[pos] = m;
        }
    }
    __syncthreads();
    const int nc = min(s_cnt, CMAX);

    const float* kl = k + (lane << 2);
    const float* vl = v + (lane << 2);

    // ---- single-pass QK+softmax+AV; one wave-uniform candidate per iter ----
    float ax = 0.f, ay = 0.f, az = 0.f, aw = 0.f, ps = 0.f;
    const int cbase = w * CPW;
    #pragma unroll
    for (int i = 0; i < CPW; i++) {
        const int ci   = cbase + i;
        const bool live = (ci < nc);
        const int row  = __builtin_amdgcn_readfirstlane(s_cand[live ? ci : 0]);
        const size_t off = (size_t)row * FEAT;
        const float4 kk = *(const float4*)(kl + off);   // 64 lanes -> contiguous 1024 B
        const float4 vv = *(const float4*)(vl + off);   // 64 lanes -> contiguous 1024 B
        float p = q4.x*kk.x;
        p = __builtin_fmaf(q4.y, kk.y, p);
        p = __builtin_fmaf(q4.z, kk.z, p);
        p = __builtin_fmaf(q4.w, kk.w, p);
        p += __shfl_xor(p, 1);
        p += __shfl_xor(p, 2);
        p += __shfl_xor(p, 4);              // full head-dot in all 8 lanes of the group
        const float e = live ? __expf(p * 0.17677669529663687f) : 0.0f;
        ps += e;
        ax = __builtin_fmaf(e, vv.x, ax);
        ay = __builtin_fmaf(e, vv.y, ay);
        az = __builtin_fmaf(e, vv.z, az);
        aw = __builtin_fmaf(e, vv.w, aw);
    }

    // ---- cross-wave combine (each thread owns (head,dims) partials) ----
    s_ax[tid] = ax; s_ay[tid] = ay; s_az[tid] = az; s_aw[tid] = aw; s_ps[tid] = ps;
    __syncthreads();

    if (tid < 64) {
        const float fax = ((s_ax[tid] + s_ax[tid+64]) + s_ax[tid+128]) + s_ax[tid+192];
        const float fay = ((s_ay[tid] + s_ay[tid+64]) + s_ay[tid+128]) + s_ay[tid+192];
        const float faz = ((s_az[tid] + s_az[tid+64]) + s_az[tid+128]) + s_az[tid+192];
        const float faw = ((s_aw[tid] + s_aw[tid+64]) + s_aw[tid+128]) + s_aw[tid+192];
        const float fps = ((s_ps[tid] + s_ps[tid+64]) + s_ps[tid+128]) + s_ps[tid+192];
        float4 r;
        if (nc > 0) { r.x = fax/fps; r.y = fay/fps; r.z = faz/fps; r.w = faw/fps; }
        else        { r.x = r.y = r.z = r.w = 0.0f; }
        *(float4*)(out + l*FEAT + (tid << 2)) = r;   // 64 lanes -> contiguous 1024 B
    }
}

extern "C" void kernel_launch(void* const* d_in, const int* in_sizes, int n_in,
                              void* d_out, int out_size, void* d_ws, size_t ws_size,
                              hipStream_t stream) {
    const float* q  = (const float*)d_in[0];
    const float* k  = (const float*)d_in[1];
    const float* v  = (const float*)d_in[2];
    const float* K0 = (const float*)d_in[3];
    const float* K1 = (const float*)d_in[4];
    const float* R  = (const float*)d_in[5];
    const float* t  = (const float*)d_in[6];
    float* out = (float*)d_out;
    (void)d_ws; (void)ws_size;
    one2many_fused<<<NPIX, 256, 0, stream>>>(q, k, v, K0, K1, R, t, out);
}